// Round 13
// baseline (268.874 us; speedup 1.0000x reference)
//
#include <hip/hip_runtime.h>
#include <cstdint>
#include <cstddef>

// B=8, C=512, H=8, d=64, HW=32, N=N1=1024
// ws f32-slot layout:
//   yp    @0         (4M)   pool out; dead after ln -> reused: kbf@0 (2M), vtbf@2M (2M)
//   ynbf  @4194304   (2M slots, bf16)  ln out
//   xbf   @6291456   (2M slots, bf16)  x transposed
//   qbf   @8388608   (2M slots, bf16)  q gemm out
//   attbf @10485760  (2M slots, bf16)  attn out
//   qwbf  @12582912, kvwbf @12713984, pwbf @12976128 (bf16 weights)
//   pooled @13107200, kvals @13111296

typedef short bf16x8 __attribute__((ext_vector_type(8)));
typedef float f32x4 __attribute__((ext_vector_type(4)));

__device__ __forceinline__ unsigned short f2bf(float f) {
    unsigned u = __float_as_uint(f);
    u = (u + 0x7fffu + ((u >> 16) & 1u)) >> 16;
    return (unsigned short)u;
}
__device__ __forceinline__ unsigned xform_u(unsigned u) {
    return (u & 0x80000000u) ? ~u : (u | 0x80000000u);
}
__device__ __forceinline__ float unxform_f(unsigned k) {
    const unsigned u = (k & 0x80000000u) ? (k & 0x7fffffffu) : ~k;
    return __uint_as_float(u);
}
// inverse normal (Hastings) for upper-tail probability pq
__device__ __forceinline__ float invnorm(float pq) {
    const float pc = pq < 0.5f ? pq : 1.f - pq;
    const float tt = sqrtf(-2.f * __logf(fmaxf(pc, 1e-20f)));
    const float zq = tt - (2.30753f + 0.27061f * tt) /
                          (1.f + tt * (0.99229f + 0.04481f * tt));
    return pq < 0.5f ? zq : -zq;
}

// ---- DPP wave64 reductions (VALU-only; result uniform via readlane 63) ----
__device__ __forceinline__ float dpp_red_add(float v) {
#define DPP_ADD(C)                                                            \
    v += __int_as_float(__builtin_amdgcn_update_dpp(                          \
        0, __float_as_int(v), C, 0xf, 0xf, true));
    DPP_ADD(0x111) DPP_ADD(0x112) DPP_ADD(0x114)
    DPP_ADD(0x118) DPP_ADD(0x142) DPP_ADD(0x143)
#undef DPP_ADD
    return __int_as_float(__builtin_amdgcn_readlane(__float_as_int(v), 63));
}
__device__ __forceinline__ float dpp_red_max(float v) {
#define DPP_MAX(C)                                                            \
    {                                                                         \
        const int t_ = __builtin_amdgcn_update_dpp(                           \
            __float_as_int(v), __float_as_int(v), C, 0xf, 0xf, false);        \
        v = fmaxf(v, __int_as_float(t_));                                     \
    }
    DPP_MAX(0x111) DPP_MAX(0x112) DPP_MAX(0x114)
    DPP_MAX(0x118) DPP_MAX(0x142) DPP_MAX(0x143)
#undef DPP_MAX
    return __int_as_float(__builtin_amdgcn_readlane(__float_as_int(v), 63));
}
__device__ __forceinline__ float dpp_red_min(float v) {
#define DPP_MIN(C)                                                            \
    {                                                                         \
        const int t_ = __builtin_amdgcn_update_dpp(                           \
            __float_as_int(v), __float_as_int(v), C, 0xf, 0xf, false);        \
        v = fminf(v, __int_as_float(t_));                                     \
    }
    DPP_MIN(0x111) DPP_MIN(0x112) DPP_MIN(0x114)
    DPP_MIN(0x118) DPP_MIN(0x142) DPP_MIN(0x143)
#undef DPP_MIN
    return __int_as_float(__builtin_amdgcn_readlane(__float_as_int(v), 63));
}

// async global->LDS, 16B per lane, dest = wave-uniform base + lane*16
__device__ __forceinline__ void stage16(const unsigned short* g,
                                        unsigned short* l) {
    __builtin_amdgcn_global_load_lds(
        (const __attribute__((address_space(1))) unsigned int*)g,
        (__attribute__((address_space(3))) unsigned int*)l, 16, 0, 0);
}

// ---------------------------------------------------------------------------
// Separable multi-scale pooling v3. One block = one (b,c) plane.
__global__ __launch_bounds__(256) void pool_kernel(const float* __restrict__ y,
                                                   float* __restrict__ yp) {
    __shared__ float pz[1280];                    // [32][40], cols 3..34 live
    __shared__ float hz3[1024], hz5[1024], hz7[1024];
    __shared__ float hm3[1024], hm5[1024], hm7[1024];
    const int bc = blockIdx.x;
    const int t = threadIdx.x;
    const float NEG = -3.402823466e38f;
    for (int i = t; i < 1280; i += 256) pz[i] = 0.f;
    __syncthreads();
    const float4 v = reinterpret_cast<const float4*>(y + (size_t)bc * 1024)[t];
    {
        const int r = t >> 3, c = (t & 7) * 4;
        float* dz = &pz[r * 40 + c + 3];
        dz[0] = v.x; dz[1] = v.y; dz[2] = v.z; dz[3] = v.w;
    }
    __syncthreads();
#pragma unroll
    for (int q = 0; q < 4; q++) {
        const int p = q * 256 + t;
        const int i = p >> 5, j = p & 31;
        const float* rz = &pz[i * 40 + j + 3];
        const float vm3 = rz[-3], vm2 = rz[-2], vm1 = rz[-1];
        const float v0 = rz[0], vp1 = rz[1], vp2 = rz[2], vp3 = rz[3];
        const float s3 = vm1 + v0 + vp1;
        const float s5 = s3 + vm2 + vp2;
        const float s7 = s5 + vm3 + vp3;
        const float am1 = (j >= 1) ? vm1 : NEG, ap1 = (j <= 30) ? vp1 : NEG;
        const float am2 = (j >= 2) ? vm2 : NEG, ap2 = (j <= 29) ? vp2 : NEG;
        const float am3 = (j >= 3) ? vm3 : NEG, ap3 = (j <= 28) ? vp3 : NEG;
        const float m3 = fmaxf(fmaxf(am1, v0), ap1);
        const float m5 = fmaxf(m3, fmaxf(am2, ap2));
        const float m7 = fmaxf(m5, fmaxf(am3, ap3));
        hz3[p] = s3; hz5[p] = s5; hz7[p] = s7;
        hm3[p] = m3; hm5[p] = m5; hm7[p] = m7;
    }
    __syncthreads();
    float* dst = yp + (size_t)bc * 1024;
#pragma unroll
    for (int q = 0; q < 4; q++) {
        const int p = q * 256 + t;
        const int i = p >> 5, j = p & 31;
        float s3 = 0.f, s5 = 0.f, s7 = 0.f;
        float m3 = NEG, m5 = NEG, m7 = NEG;
#pragma unroll
        for (int dr = -3; dr <= 3; dr++) {
            const int rv = i + dr;
            const bool ok = (rv >= 0) && (rv <= 31);
            const int rc = rv < 0 ? 0 : (rv > 31 ? 31 : rv);
            const int ic = rc * 32 + j;
            const int ad = dr < 0 ? -dr : dr;
            s7 += ok ? hz7[ic] : 0.f;
            m7 = fmaxf(m7, ok ? hm7[ic] : NEG);
            if (ad <= 2) {
                s5 += ok ? hz5[ic] : 0.f;
                m5 = fmaxf(m5, ok ? hm5[ic] : NEG);
            }
            if (ad <= 1) {
                s3 += ok ? hz3[ic] : 0.f;
                m3 = fmaxf(m3, ok ? hm3[ic] : NEG);
            }
        }
        dst[p] = s3 * (1.f / 9.f) + s5 * (1.f / 25.f) + s7 * (1.f / 49.f) +
                 m3 + m5 + m7;
    }
}

// ---------------------------------------------------------------------------
__device__ __forceinline__ float block_sum256(float v, volatile float* scr) {
    v = dpp_red_add(v);
    const int t = threadIdx.x;
    __syncthreads();
    if ((t & 63) == 0) scr[t >> 6] = v;
    __syncthreads();
    return scr[0] + scr[1] + scr[2] + scr[3];
}

// LayerNorm v4: coalesced tile load, wave-local rows, DPP reductions.
__global__ __launch_bounds__(256) void ln_kernel3(const float* __restrict__ yp,
                                                  const float* __restrict__ g,
                                                  const float* __restrict__ bt,
                                                  unsigned short* __restrict__ ynbf) {
    __shared__ float tile[512][17];
    const int blk = blockIdx.x;           // b*64 + ntile
    const int b = blk >> 6;
    const int n0 = (blk & 63) * 16;
    const int t = threadIdx.x;
#pragma unroll
    for (int r = 0; r < 8; ++r) {
        const int c = r * 64 + (t >> 2);
        const int nn = (t & 3) * 4;
        const float4 v = *reinterpret_cast<const float4*>(
            &yp[((size_t)(b * 512 + c)) * 1024 + n0 + nn]);
        tile[c][nn + 0] = v.x; tile[c][nn + 1] = v.y;
        tile[c][nn + 2] = v.z; tile[c][nn + 3] = v.w;
    }
    const int w = t >> 6, lane = t & 63;
    float gv[8], bv[8];
#pragma unroll
    for (int j = 0; j < 8; j++) {
        gv[j] = g[lane + 64 * j];
        bv[j] = bt[lane + 64 * j];
    }
    __syncthreads();
#pragma unroll
    for (int rr = 0; rr < 4; ++rr) {
        const int n = w * 4 + rr;
        float v[8];
        float ls = 0.f;
#pragma unroll
        for (int j = 0; j < 8; j++) {
            v[j] = tile[lane + 64 * j][n];
            ls += v[j];
        }
        ls = dpp_red_add(ls);
        const float mu = ls * (1.f / 512.f);
        float ls2 = 0.f;
#pragma unroll
        for (int j = 0; j < 8; j++) {
            const float d = v[j] - mu;
            ls2 = fmaf(d, d, ls2);
        }
        ls2 = dpp_red_add(ls2);
        const float rs = rsqrtf(ls2 * (1.f / 512.f) + 1e-5f);
        unsigned short* o = ynbf + ((size_t)(b * 1024 + n0 + n)) * 512;
#pragma unroll
        for (int j = 0; j < 8; j++)
            o[lane + 64 * j] = f2bf((v[j] - mu) * rs * gv[j] + bv[j]);
    }
}

// ---------------------------------------------------------------------------
__global__ __launch_bounds__(256) void pooled_kernel(const float* __restrict__ x,
                                                     float* __restrict__ pooled) {
    __shared__ float scr[4];
    const int bc = blockIdx.x, t = threadIdx.x;
    const float4 v = reinterpret_cast<const float4*>(x + (size_t)bc * 1024)[t];
    const float s = block_sum256(v.x + v.y + v.z + v.w, scr);
    if (t == 0) pooled[bc] = s * (1.f / 1024.f);
}

__global__ __launch_bounds__(128) void mlp_kernel(const float* __restrict__ pooled,
                                                  const float* __restrict__ w1,
                                                  const float* __restrict__ b1,
                                                  const float* __restrict__ w2,
                                                  const float* __restrict__ b2,
                                                  int* __restrict__ kvals) {
    __shared__ float pl[512];
    __shared__ float h1[128];
    __shared__ float lg[8];
    const int b = blockIdx.x, t = threadIdx.x;
#pragma unroll
    for (int i = 0; i < 4; i++) pl[t + i * 128] = pooled[b * 512 + t + i * 128];
    __syncthreads();
    float acc = b1[t];
    for (int i = 0; i < 512; i++) acc = fmaf(pl[i], w1[t * 512 + i], acc);
    h1[t] = fmaxf(acc, 0.f);
    __syncthreads();
    if (t < 8) {
        float a = b2[t];
        for (int i = 0; i < 128; i++) a = fmaf(h1[i], w2[t * 128 + i], a);
        lg[t] = a;
    }
    __syncthreads();
    if (t == 0) {
        float m = lg[0];
#pragma unroll
        for (int h = 1; h < 8; h++) m = fmaxf(m, lg[h]);
        float e[8], s = 0.f;
#pragma unroll
        for (int h = 0; h < 8; h++) { e[h] = expf(lg[h] - m); s += e[h]; }
#pragma unroll
        for (int h = 0; h < 8; h++) {
            const float p = e[h] / s;
            int kv = (int)floorf(p * 1024.f);
            kv = kv < 1 ? 1 : (kv > 1024 ? 1024 : kv);
            kvals[b * 8 + h] = kv;
        }
    }
}

// ---------------------------------------------------------------------------
// All three weight matrices -> bf16 in one launch.
__global__ __launch_bounds__(256) void convw(const float* __restrict__ qw,
                                             const float* __restrict__ kvw,
                                             const float* __restrict__ pw,
                                             unsigned short* __restrict__ dq,
                                             unsigned short* __restrict__ dkv,
                                             unsigned short* __restrict__ dp) {
    const int gid = blockIdx.x * 256 + threadIdx.x;
    const float* s; unsigned short* d; int off;
    if (gid < 65536) { s = qw; d = dq; off = gid * 4; }
    else if (gid < 196608) { s = kvw; d = dkv; off = gid * 4 - 262144; }
    else { s = pw; d = dp; off = gid * 4 - 786432; }
    const float4 v = *reinterpret_cast<const float4*>(&s[off]);
    ushort4 o;
    o.x = f2bf(v.x); o.y = f2bf(v.y); o.z = f2bf(v.z); o.w = f2bf(v.w);
    *reinterpret_cast<ushort4*>(&d[off]) = o;
}

// x (b,c,n) fp32 -> xbf (b,n,c) bf16
__global__ __launch_bounds__(256) void xtrans(const float* __restrict__ x,
                                              unsigned short* __restrict__ xbf) {
    __shared__ float tile[32][36];
    const int blk = blockIdx.x;       // b(3b) | cg(4b) | ng(5b)
    const int ng = blk & 31;
    const int cg = (blk >> 5) & 15;
    const int b = blk >> 9;
    const int c0 = cg * 32, n0 = ng * 32;
    const int t = threadIdx.x;
    {
        const int cc = t >> 3, nn = (t & 7) * 4;
        const float4 v = *reinterpret_cast<const float4*>(
            &x[((size_t)(b * 512 + c0 + cc)) * 1024 + n0 + nn]);
        *reinterpret_cast<float4*>(&tile[cc][nn]) = v;
    }
    __syncthreads();
    {
        const int n = t >> 3, cb = (t & 7) * 4;
        ushort4 o;
        o.x = f2bf(tile[cb + 0][n]); o.y = f2bf(tile[cb + 1][n]);
        o.z = f2bf(tile[cb + 2][n]); o.w = f2bf(tile[cb + 3][n]);
        *reinterpret_cast<ushort4*>(
            &xbf[((size_t)(b * 1024 + n0 + n)) * 512 + c0 + cb]) = o;
    }
}

// ---------------------------------------------------------------------------
// MFMA bf16 GEMM core: C[128x128 tile] = A[M,512] @ W[Nout,512]^T
template <int EPI>
__device__ __forceinline__ void gemm_core(const unsigned short* __restrict__ A,
                                          const unsigned short* __restrict__ W,
                                          const float* __restrict__ bias,
                                          void* __restrict__ out0,
                                          unsigned short* __restrict__ out1,
                                          int Nout, int bx, int by,
                                          unsigned short* As,
                                          unsigned short* Ws) {
    const int t = threadIdx.x;
    const int w = t >> 6, lane = t & 63;
    const int l15 = lane & 15, l4 = lane >> 4;
    const int n0 = bx * 128;
    const int m0 = by * 128;
    const int wm = (w >> 1) * 64, wn = (w & 1) * 64;
    f32x4 acc[4][4];
#pragma unroll
    for (int i = 0; i < 4; i++)
#pragma unroll
        for (int j = 0; j < 4; j++) acc[i][j] = (f32x4){0.f, 0.f, 0.f, 0.f};
    const int lrow = lane >> 3;               // 0..7
    const int lslot = (lane & 7) ^ lrow;      // inverse-swizzled 16B slot
    const unsigned short* aG = A + (size_t)(m0 + lrow) * 512 + lslot * 8;
    const unsigned short* wG = W + (size_t)(n0 + lrow) * 512 + lslot * 8;
#pragma unroll 1
    for (int k0 = 0; k0 < 512; k0 += 64) {
        __syncthreads();
#pragma unroll
        for (int p = 0; p < 4; p++) {
            const int rb = p * 32 + w * 8;
            stage16(aG + (size_t)rb * 512 + k0, &As[rb * 64]);
            stage16(wG + (size_t)rb * 512 + k0, &Ws[rb * 64]);
        }
        __syncthreads();
#pragma unroll
        for (int kk = 0; kk < 2; kk++) {
            bf16x8 af[4], wf[4];
#pragma unroll
            for (int f = 0; f < 4; f++) {
                const int ra = wm + f * 16 + l15;
                af[f] = *reinterpret_cast<const bf16x8*>(
                    &As[ra * 64 + (((kk * 4 + l4) ^ (ra & 7)) << 3)]);
                const int rw = wn + f * 16 + l15;
                wf[f] = *reinterpret_cast<const bf16x8*>(
                    &Ws[rw * 64 + (((kk * 4 + l4) ^ (rw & 7)) << 3)]);
            }
#pragma unroll
            for (int fm = 0; fm < 4; fm++)
#pragma unroll
                for (int fn = 0; fn < 4; fn++)
                    acc[fm][fn] = __builtin_amdgcn_mfma_f32_16x16x32_bf16(
                        af[fm], wf[fn], acc[fm][fn], 0, 0, 0);
        }
    }
    if (EPI == 0) {
        unsigned short* C = (unsigned short*)out0;
#pragma unroll
        for (int fm = 0; fm < 4; fm++) {
            const int row = m0 + wm + fm * 16 + l4 * 4;
#pragma unroll
            for (int fn = 0; fn < 4; fn++) {
                const int col = n0 + wn + fn * 16 + l15;
#pragma unroll
                for (int q = 0; q < 4; q++)
                    C[(size_t)(row + q) * Nout + col] = f2bf(acc[fm][fn][q]);
            }
        }
    } else if (EPI == 1) {
        unsigned short* kb = (unsigned short*)out0;
        const int b = m0 >> 10;
        const int cw = n0 + wn;
        const bool isv = cw >= 512;
        const int hh = (cw & 511) >> 6;
        const size_t bh = (size_t)(b * 8 + hh);
#pragma unroll
        for (int fm = 0; fm < 4; fm++) {
            const int n = (m0 + wm + fm * 16 + l4 * 4) & 1023;
#pragma unroll
            for (int fn = 0; fn < 4; fn++) {
                const int d = fn * 16 + l15;
                if (!isv) {
#pragma unroll
                    for (int q = 0; q < 4; q++)
                        kb[(bh * 1024 + n + q) * 64 + d] = f2bf(acc[fm][fn][q]);
                } else {
                    ushort4 v4;
                    v4.x = f2bf(acc[fm][fn][0]); v4.y = f2bf(acc[fm][fn][1]);
                    v4.z = f2bf(acc[fm][fn][2]); v4.w = f2bf(acc[fm][fn][3]);
                    *reinterpret_cast<ushort4*>(&out1[(bh * 64 + d) * 1024 + n]) = v4;
                }
            }
        }
    } else {
        float* outp = (float*)out0;
        const int b = m0 >> 10;
#pragma unroll
        for (int fm = 0; fm < 4; fm++) {
            const int n = (m0 + wm + fm * 16 + l4 * 4) & 1023;
#pragma unroll
            for (int fn = 0; fn < 4; fn++) {
                const int c = n0 + wn + fn * 16 + l15;
                const float bv = bias[c];
                float4 o;
                o.x = acc[fm][fn][0] + bv; o.y = acc[fm][fn][1] + bv;
                o.z = acc[fm][fn][2] + bv; o.w = acc[fm][fn][3] + bv;
                *reinterpret_cast<float4*>(
                    &outp[((size_t)(b * 512) + c) * 1024 + n]) = o;
            }
        }
    }
}

// Fused kv + q GEMM: blocks 0..511 -> kv (EPI 1), 512..767 -> q (EPI 0).
__global__ __launch_bounds__(256, 4) void gemm_qkv(
    const unsigned short* __restrict__ ynbf,
    const unsigned short* __restrict__ kvwbf,
    const unsigned short* __restrict__ xbf,
    const unsigned short* __restrict__ qwbf,
    unsigned short* __restrict__ kbf,
    unsigned short* __restrict__ vtbf,
    unsigned short* __restrict__ qbf) {
    __shared__ unsigned short As[128 * 64];
    __shared__ unsigned short Ws[128 * 64];
    const int blk = blockIdx.x;
    if (blk < 512) {
        gemm_core<1>(ynbf, kvwbf, nullptr, kbf, vtbf, 1024, blk & 7, blk >> 3,
                     As, Ws);
    } else {
        const int i = blk - 512;
        gemm_core<0>(xbf, qwbf, nullptr, qbf, nullptr, 512, i & 3, i >> 2,
                     As, Ws);
    }
}

// proj GEMM (EPI 2)
__global__ __launch_bounds__(256, 4) void gemm_proj(
    const unsigned short* __restrict__ attbf,
    const unsigned short* __restrict__ pwbf,
    const float* __restrict__ bias,
    float* __restrict__ out) {
    __shared__ unsigned short As[128 * 64];
    __shared__ unsigned short Ws[128 * 64];
    gemm_core<2>(attbf, pwbf, bias, out, nullptr, 512, blockIdx.x, blockIdx.y,
                 As, Ws);
}

// ---------------------------------------------------------------------------
// count of f[i] >= Tf across the wave (wave-uniform result)
__device__ __forceinline__ int cntF(const float* f, float Tf) {
    int c = 0;
#pragma unroll
    for (int i = 0; i < 16; i++)
        c += (int)__popcll(__ballot(f[i] >= Tf));
    return c;
}

// Fused attention v12: attn9 structure + multi-probe (3 thresholds/round)
// exact top-k search + V register prefetch under the search.
// 16 waves, 1 query row per wave, f32 logits.
__global__ __launch_bounds__(1024, 8) void attn12(
    const unsigned short* __restrict__ qbf,
    const unsigned short* __restrict__ kbf,
    const unsigned short* __restrict__ vtbf,
    const int* __restrict__ kvals,
    const float* __restrict__ temp,
    unsigned short* __restrict__ attbf) {
    __shared__ float smem[16384];   // 64 KB: logits -> (P bf16 | partials)
    const int bid = blockIdx.x;
    const int swz = (bid & 7) * 512 + (bid >> 3);   // XCD-contiguous bh groups
    const int bh = swz >> 6;
    const int tile = swz & 63;
    const int b = bh >> 3, h = bh & 7;
    const int n0 = tile * 16;
    const int t = threadIdx.x;
    const int lane = t & 63, w = t >> 6;   // w = 0..15 (also: my query row)
    const int l15 = lane & 15, l4 = lane >> 4;

    const float tempv = temp[h];
    const int kv_s = __builtin_amdgcn_readfirstlane(kvals[b * 8 + h]);

    // ---- Phase 1: QK^T swapped (A=K, B=Q): lane holds 4 consecutive keys ----
    {
        const unsigned short* qp =
            qbf + ((size_t)(b * 1024 + n0 + l15)) * 512 + h * 64 + l4 * 8;
        const bf16x8 qa0 = *reinterpret_cast<const bf16x8*>(qp);
        const bf16x8 qa1 = *reinterpret_cast<const bf16x8*>(qp + 32);
        const unsigned short* kbase = kbf + (size_t)bh * 65536;
#pragma unroll
        for (int f = 0; f < 4; f++) {
            const int key = w * 64 + f * 16 + l15;
            const unsigned short* kp = kbase + (size_t)key * 64 + l4 * 8;
            const bf16x8 kb0 = *reinterpret_cast<const bf16x8*>(kp);
            const bf16x8 kb1 = *reinterpret_cast<const bf16x8*>(kp + 32);
            f32x4 acc = {0.f, 0.f, 0.f, 0.f};
            acc = __builtin_amdgcn_mfma_f32_16x16x32_bf16(kb0, qa0, acc, 0, 0, 0);
            acc = __builtin_amdgcn_mfma_f32_16x16x32_bf16(kb1, qa1, acc, 0, 0, 0);
            const int blkidx = w * 16 + f * 4 + l4;      // 16B block in row
            float4 o;
            o.x = acc[0] * tempv; o.y = acc[1] * tempv;
            o.z = acc[2] * tempv; o.w = acc[3] * tempv;
            *reinterpret_cast<float4*>(
                &smem[l15 * 1024 + ((blkidx ^ (l15 & 7)) << 2)]) = o;
        }
    }
    __syncthreads();

    // ---- Phase 2: my row -> f[16] (unswizzled read); fused stats ----
    float f[16];
    float vmn = 3.402823466e38f, vmx = -3.402823466e38f;
    float fs = 0.f;
#pragma unroll
    for (int i = 0; i < 4; i++) {
        const int gblk = i * 64 + lane;                  // keys gblk*4..+3
        const float4 f0 = *reinterpret_cast<const float4*>(
            &smem[w * 1024 + ((gblk ^ (w & 7)) << 2)]);
        f[4 * i + 0] = f0.x; f[4 * i + 1] = f0.y;
        f[4 * i + 2] = f0.z; f[4 * i + 3] = f0.w;
#pragma unroll
        for (int j = 0; j < 4; j++) {
            const float v = f[4 * i + j];
            vmn = fminf(vmn, v);
            vmx = fmaxf(vmx, v);
            fs += v;
        }
    }
    __syncthreads();     // logits LDS dead -> P overlays

    // ---- V prefetch: first 4 PV fragments issue now; latency hides under
    //      the search. V depends on nothing block-local.
    const int kseg = w >> 2, cf = w & 3;
    const unsigned short* vtb =
        vtbf + (size_t)bh * 65536 + (size_t)(cf * 16 + l15) * 1024;
    const bf16x8 vp0 =
        *reinterpret_cast<const bf16x8*>(vtb + kseg * 256 + 0 * 32 + l4 * 8);
    const bf16x8 vp1 =
        *reinterpret_cast<const bf16x8*>(vtb + kseg * 256 + 1 * 32 + l4 * 8);
    const bf16x8 vp2 =
        *reinterpret_cast<const bf16x8*>(vtb + kseg * 256 + 2 * 32 + l4 * 8);
    const bf16x8 vp3 =
        *reinterpret_cast<const bf16x8*>(vtb + kseg * 256 + 3 * 32 + l4 * 8);

    vmn = dpp_red_min(vmn);
    vmx = dpp_red_max(vmx);
    fs = dpp_red_add(fs);

    // ---- Phase 3: exact threshold via multi-probe bracket search ----
    float thrF;
    {
        const int cmx = __builtin_amdgcn_readfirstlane(cntF(f, vmx));
        if (cmx >= kv_s) {
            thrF = vmx;
        } else if (kv_s >= 1024) {
            thrF = vmn;
        } else {
            const float mu = fs * (1.f / 1024.f);
            const float sg = fmaxf((vmx - mu) * 0.3125f, 1e-12f);
            unsigned lo = xform_u(__float_as_uint(vmn));
            unsigned hi = xform_u(__float_as_uint(vmx));
            int clo = 1024, chi = cmx;
            // seed probes: Gaussian quantiles for counts {k+16, k, k-16}
            const int kp1 = (kv_s + 16 > 1023) ? 1023 : kv_s + 16;
            const int km1 = (kv_s - 16 < 1) ? 1 : kv_s - 16;
            const float t1s = fmaf(invnorm((float)kp1 * (1.f / 1024.f)), sg, mu);
            const float t2s = fmaf(invnorm((float)kv_s * (1.f / 1024.f)), sg, mu);
            const float t3s = fmaf(invnorm((float)km1 * (1.f / 1024.f)), sg, mu);
            unsigned u2 = xform_u(__float_as_uint(t2s));
            if (u2 <= lo) u2 = lo + 1;
            if (u2 >= hi) u2 = hi - 1;
            unsigned u1 = xform_u(__float_as_uint(t1s));
            if (u1 <= lo) u1 = lo + 1;
            if (u1 > u2) u1 = u2;
            unsigned u3 = xform_u(__float_as_uint(t3s));
            if (u3 < u2) u3 = u2;
            if (u3 >= hi) u3 = hi - 1;
            bool done = false;
            thrF = vmn;
#pragma unroll 1
            for (int it = 0; it < 24; ++it) {
                const float T1f = unxform_f(u1);
                const float T2f = unxform_f(u2);
                const float T3f = unxform_f(u3);
                int c1 = 0, c2 = 0, c3 = 0;
#pragma unroll
                for (int i = 0; i < 16; i++) {
                    c1 += (int)__popcll(__ballot(f[i] >= T1f));
                    c2 += (int)__popcll(__ballot(f[i] >= T2f));
                    c3 += (int)__popcll(__ballot(f[i] >= T3f));
                }
                c1 = __builtin_amdgcn_readfirstlane(c1);
                c2 = __builtin_amdgcn_readfirstlane(c2);
                c3 = __builtin_amdgcn_readfirstlane(c3);
                if (c2 == kv_s) { thrF = T2f; done = true; break; }
                if (c1 == kv_s) { thrF = T1f; done = true; break; }
                if (c3 == kv_s) { thrF = T3f; done = true; break; }
                if (c1 < kv_s) { hi = u1; chi = c1; }
                else if (c2 < kv_s) { lo = u1; clo = c1; hi = u2; chi = c2; }
                else if (c3 < kv_s) { lo = u2; clo = c2; hi = u3; chi = c3; }
                else { lo = u3; clo = c3; }
                if (hi - lo <= 1u) { thrF = unxform_f(lo); done = true; break; }
                if ((it & 3) == 2) {
                    // uniform trisection safety round
                    unsigned q = (hi - lo) >> 2;
                    if (q == 0) q = 1;
                    u1 = lo + q;
                    u2 = lo + ((hi - lo) >> 1);
                    u3 = hi - q;
                    if (u1 > u2) u1 = u2;
                    if (u3 < u2) u3 = u2;
                } else {
                    const float flo = unxform_f(lo), fhi = unxform_f(hi);
                    const float den = (float)(clo - chi);
                    const float spn = fhi - flo;
                    int dd = (clo - chi) >> 3;
                    if (dd < 1) dd = 1;
                    const float g2 = flo + ((float)(clo - kv_s) / den) * spn;
                    const float g1 = flo + ((float)(clo - kv_s - dd) / den) * spn;
                    const float g3 = flo + ((float)(clo - kv_s + dd) / den) * spn;
                    u2 = xform_u(__float_as_uint(g2));
                    if (u2 <= lo) u2 = lo + 1;
                    if (u2 >= hi) u2 = hi - 1;
                    u1 = xform_u(__float_as_uint(g1));
                    if (u1 <= lo) u1 = lo + 1;
                    if (u1 > u2) u1 = u2;
                    u3 = xform_u(__float_as_uint(g3));
                    if (u3 < u2) u3 = u2;
                    if (u3 >= hi) u3 = hi - 1;
                }
            }
            if (!done) {
                // exact bisect fallback (ties / pathological)
                while (hi - lo > 1u) {
                    const unsigned Tm = lo + ((hi - lo) >> 1);
                    const int ct = __builtin_amdgcn_readfirstlane(
                        cntF(f, unxform_f(Tm)));
                    if (ct == kv_s) { lo = Tm; break; }
                    if (ct > kv_s) lo = Tm; else hi = Tm;
                }
                thrF = unxform_f(lo);
            }
        }
    }

    // ---- Phase 3b: softmax(attn*mask) in place -> bf16 P (cvt_pk, swizzled) ----
    unsigned short* P = (unsigned short*)smem;
    {
        const float mx = (thrF > vmn) ? fmaxf(vmx, 0.f) : vmx;
        float s = 0.f;
#pragma unroll
        for (int i = 0; i < 16; i++) {
            const float g = (f[i] >= thrF) ? f[i] : 0.f;
            const float e = __expf(g - mx);
            f[i] = e;
            s += e;
        }
        s = dpp_red_add(s);
        const float inv = 1.f / s;
#pragma unroll
        for (int g4 = 0; g4 < 4; g4++) {
            unsigned lo32, hi32;
            const float a0 = f[g4 * 4 + 0] * inv, a1 = f[g4 * 4 + 1] * inv;
            const float a2 = f[g4 * 4 + 2] * inv, a3 = f[g4 * 4 + 3] * inv;
            asm("v_cvt_pk_bf16_f32 %0, %1, %2" : "=v"(lo32) : "v"(a0), "v"(a1));
            asm("v_cvt_pk_bf16_f32 %0, %1, %2" : "=v"(hi32) : "v"(a2), "v"(a3));
            uint2 pk; pk.x = lo32; pk.y = hi32;
            *reinterpret_cast<uint2*>(
                &P[w * 1024 + ((((lane >> 1) + 32 * g4) ^ (w & 7)) << 3) +
                   (lane & 1) * 4]) = pk;
        }
    }
    __syncthreads();

    // ---- Phase 4: PV; wave w -> (kseg of 256 keys, cf of 16 d). First 4
    //      V fragments come from the prefetch registers.
    f32x4 pacc = {0.f, 0.f, 0.f, 0.f};
    {
        const int kb0 = kseg * 256;
        const int g0 = (kb0 >> 3) + l4;
        const bf16x8 pa0 = *reinterpret_cast<const bf16x8*>(
            &P[l15 * 1024 + (((g0 + 0) ^ (l15 & 7)) << 3)]);
        pacc = __builtin_amdgcn_mfma_f32_16x16x32_bf16(pa0, vp0, pacc, 0, 0, 0);
        const bf16x8 pa1 = *reinterpret_cast<const bf16x8*>(
            &P[l15 * 1024 + (((g0 + 4) ^ (l15 & 7)) << 3)]);
        pacc = __builtin_amdgcn_mfma_f32_16x16x32_bf16(pa1, vp1, pacc, 0, 0, 0);
        const bf16x8 pa2 = *reinterpret_cast<const bf16x8*>(
            &P[l15 * 1024 + (((g0 + 8) ^ (l15 & 7)) << 3)]);
        pacc = __builtin_amdgcn_mfma_f32_16x16x32_bf16(pa2, vp2, pacc, 0, 0, 0);
        const bf16x8 pa3 = *reinterpret_cast<const bf16x8*>(
            &P[l15 * 1024 + (((g0 + 12) ^ (l15 & 7)) << 3)]);
        pacc = __builtin_amdgcn_mfma_f32_16x16x32_bf16(pa3, vp3, pacc, 0, 0, 0);
#pragma unroll
        for (int s8 = 4; s8 < 8; s8++) {
            const int kb = kseg * 256 + s8 * 32;
            const int g = (kb >> 3) + l4;
            const bf16x8 pa = *reinterpret_cast<const bf16x8*>(
                &P[l15 * 1024 + ((g ^ (l15 & 7)) << 3)]);
            const bf16x8 vb =
                *reinterpret_cast<const bf16x8*>(vtb + kb + l4 * 8);
            pacc = __builtin_amdgcn_mfma_f32_16x16x32_bf16(pa, vb, pacc, 0, 0, 0);
        }
    }
    __syncthreads();     // P reads done -> reuse smem for partials
    float* part = smem;  // [4 kseg][16 row][66]
#pragma unroll
    for (int q = 0; q < 4; q++)
        part[kseg * 1056 + (l4 * 4 + q) * 66 + cf * 16 + l15] = pacc[q];
    __syncthreads();
    {
        const float s = part[w * 66 + lane] + part[1056 + w * 66 + lane] +
                        part[2112 + w * 66 + lane] + part[3168 + w * 66 + lane];
        attbf[((size_t)(b * 1024 + n0 + w)) * 512 + h * 64 + lane] = f2bf(s);
    }
}

// ---------------------------------------------------------------------------
extern "C" void kernel_launch(void* const* d_in, const int* in_sizes, int n_in,
                              void* d_out, int out_size, void* d_ws, size_t ws_size,
                              hipStream_t stream) {
    const float* x = (const float*)d_in[0];
    const float* y = (const float*)d_in[1];
    const float* temp = (const float*)d_in[2];
    const float* q_w = (const float*)d_in[3];
    const float* kv_w = (const float*)d_in[4];
    const float* proj_w = (const float*)d_in[5];
    const float* proj_b = (const float*)d_in[6];
    const float* dk_w1 = (const float*)d_in[7];
    const float* dk_b1 = (const float*)d_in[8];
    const float* dk_w2 = (const float*)d_in[9];
    const float* dk_b2 = (const float*)d_in[10];
    const float* ln_g = (const float*)d_in[11];
    const float* ln_b = (const float*)d_in[12];
    float* out = (float*)d_out;
    float* ws = (float*)d_ws;

    float* yp = ws;
    unsigned short* ynbf = (unsigned short*)(ws + 4194304);
    unsigned short* xbf = (unsigned short*)(ws + 6291456);
    unsigned short* qbf = (unsigned short*)(ws + 8388608);
    unsigned short* attbf = (unsigned short*)(ws + 10485760);
    unsigned short* qwbf = (unsigned short*)(ws + 12582912);
    unsigned short* kvwbf = (unsigned short*)(ws + 12713984);
    unsigned short* pwbf = (unsigned short*)(ws + 12976128);
    float* pooled = ws + 13107200;
    int* kvals = (int*)(ws + 13111296);
    unsigned short* kbf = (unsigned short*)ws;               // reuse yp after ln
    unsigned short* vtbf = (unsigned short*)(ws + 2097152);  // reuse yp after ln

    pool_kernel<<<4096, 256, 0, stream>>>(y, yp);
    xtrans<<<4096, 256, 0, stream>>>(x, xbf);
    pooled_kernel<<<4096, 256, 0, stream>>>(x, pooled);
    mlp_kernel<<<8, 128, 0, stream>>>(pooled, dk_w1, dk_b1, dk_w2, dk_b2, kvals);
    convw<<<1024, 256, 0, stream>>>(q_w, kv_w, proj_w, qwbf, kvwbf, pwbf);
    ln_kernel3<<<512, 256, 0, stream>>>(yp, ln_g, ln_b, ynbf);
    gemm_qkv<<<768, 256, 0, stream>>>(ynbf, kvwbf, xbf, qwbf, kbf, vtbf, qbf);
    attn12<<<4096, 1024, 0, stream>>>(qbf, kbf, vtbf, kvals, temp, attbf);
    gemm_proj<<<dim3(4, 64), 256, 0, stream>>>(attbf, pwbf, proj_b, out);
}

// Round 14
// 258.269 us; speedup vs baseline: 1.0411x; 1.0411x over previous
//
#include <hip/hip_runtime.h>
#include <cstdint>
#include <cstddef>

// B=8, C=512, H=8, d=64, HW=32, N=N1=1024
// ws f32-slot layout:
//   yp    @0         (4M)   pool out; dead after ln -> reused: kbf@0 (2M), vtbf@2M (2M)
//   ynbf  @4194304   (2M slots, bf16)  ln out
//   xbf   @6291456   (2M slots, bf16)  x transposed
//   qbf   @8388608   (2M slots, bf16)  q gemm out
//   attbf @10485760  (2M slots, bf16)  attn out
//   qwbf  @12582912, kvwbf @12713984, pwbf @12976128 (bf16 weights)
//   pooled @13107200, kvals @13111296

typedef short bf16x8 __attribute__((ext_vector_type(8)));
typedef float f32x4 __attribute__((ext_vector_type(4)));

__device__ __forceinline__ unsigned short f2bf(float f) {
    unsigned u = __float_as_uint(f);
    u = (u + 0x7fffu + ((u >> 16) & 1u)) >> 16;
    return (unsigned short)u;
}
__device__ __forceinline__ unsigned xform_u(unsigned u) {
    return (u & 0x80000000u) ? ~u : (u | 0x80000000u);
}
__device__ __forceinline__ float unxform_f(unsigned k) {
    const unsigned u = (k & 0x80000000u) ? (k & 0x7fffffffu) : ~k;
    return __uint_as_float(u);
}

// ---- DPP wave64 reductions (VALU-only; result uniform via readlane 63) ----
__device__ __forceinline__ float dpp_red_add(float v) {
#define DPP_ADD(C)                                                            \
    v += __int_as_float(__builtin_amdgcn_update_dpp(                          \
        0, __float_as_int(v), C, 0xf, 0xf, true));
    DPP_ADD(0x111) DPP_ADD(0x112) DPP_ADD(0x114)
    DPP_ADD(0x118) DPP_ADD(0x142) DPP_ADD(0x143)
#undef DPP_ADD
    return __int_as_float(__builtin_amdgcn_readlane(__float_as_int(v), 63));
}
__device__ __forceinline__ float dpp_red_max(float v) {
#define DPP_MAX(C)                                                            \
    {                                                                         \
        const int t_ = __builtin_amdgcn_update_dpp(                           \
            __float_as_int(v), __float_as_int(v), C, 0xf, 0xf, false);        \
        v = fmaxf(v, __int_as_float(t_));                                     \
    }
    DPP_MAX(0x111) DPP_MAX(0x112) DPP_MAX(0x114)
    DPP_MAX(0x118) DPP_MAX(0x142) DPP_MAX(0x143)
#undef DPP_MAX
    return __int_as_float(__builtin_amdgcn_readlane(__float_as_int(v), 63));
}
__device__ __forceinline__ float dpp_red_min(float v) {
#define DPP_MIN(C)                                                            \
    {                                                                         \
        const int t_ = __builtin_amdgcn_update_dpp(                           \
            __float_as_int(v), __float_as_int(v), C, 0xf, 0xf, false);        \
        v = fminf(v, __int_as_float(t_));                                     \
    }
    DPP_MIN(0x111) DPP_MIN(0x112) DPP_MIN(0x114)
    DPP_MIN(0x118) DPP_MIN(0x142) DPP_MIN(0x143)
#undef DPP_MIN
    return __int_as_float(__builtin_amdgcn_readlane(__float_as_int(v), 63));
}

// async global->LDS, 16B per lane, dest = wave-uniform base + lane*16
__device__ __forceinline__ void stage16(const unsigned short* g,
                                        unsigned short* l) {
    __builtin_amdgcn_global_load_lds(
        (const __attribute__((address_space(1))) unsigned int*)g,
        (__attribute__((address_space(3))) unsigned int*)l, 16, 0, 0);
}

// ---------------------------------------------------------------------------
// Separable multi-scale pooling v3. One block = one (b,c) plane.
__global__ __launch_bounds__(256) void pool_kernel(const float* __restrict__ y,
                                                   float* __restrict__ yp) {
    __shared__ float pz[1280];                    // [32][40], cols 3..34 live
    __shared__ float hz3[1024], hz5[1024], hz7[1024];
    __shared__ float hm3[1024], hm5[1024], hm7[1024];
    const int bc = blockIdx.x;
    const int t = threadIdx.x;
    const float NEG = -3.402823466e38f;
    for (int i = t; i < 1280; i += 256) pz[i] = 0.f;
    __syncthreads();
    const float4 v = reinterpret_cast<const float4*>(y + (size_t)bc * 1024)[t];
    {
        const int r = t >> 3, c = (t & 7) * 4;
        float* dz = &pz[r * 40 + c + 3];
        dz[0] = v.x; dz[1] = v.y; dz[2] = v.z; dz[3] = v.w;
    }
    __syncthreads();
#pragma unroll
    for (int q = 0; q < 4; q++) {
        const int p = q * 256 + t;
        const int i = p >> 5, j = p & 31;
        const float* rz = &pz[i * 40 + j + 3];
        const float vm3 = rz[-3], vm2 = rz[-2], vm1 = rz[-1];
        const float v0 = rz[0], vp1 = rz[1], vp2 = rz[2], vp3 = rz[3];
        const float s3 = vm1 + v0 + vp1;
        const float s5 = s3 + vm2 + vp2;
        const float s7 = s5 + vm3 + vp3;
        const float am1 = (j >= 1) ? vm1 : NEG, ap1 = (j <= 30) ? vp1 : NEG;
        const float am2 = (j >= 2) ? vm2 : NEG, ap2 = (j <= 29) ? vp2 : NEG;
        const float am3 = (j >= 3) ? vm3 : NEG, ap3 = (j <= 28) ? vp3 : NEG;
        const float m3 = fmaxf(fmaxf(am1, v0), ap1);
        const float m5 = fmaxf(m3, fmaxf(am2, ap2));
        const float m7 = fmaxf(m5, fmaxf(am3, ap3));
        hz3[p] = s3; hz5[p] = s5; hz7[p] = s7;
        hm3[p] = m3; hm5[p] = m5; hm7[p] = m7;
    }
    __syncthreads();
    float* dst = yp + (size_t)bc * 1024;
#pragma unroll
    for (int q = 0; q < 4; q++) {
        const int p = q * 256 + t;
        const int i = p >> 5, j = p & 31;
        float s3 = 0.f, s5 = 0.f, s7 = 0.f;
        float m3 = NEG, m5 = NEG, m7 = NEG;
#pragma unroll
        for (int dr = -3; dr <= 3; dr++) {
            const int rv = i + dr;
            const bool ok = (rv >= 0) && (rv <= 31);
            const int rc = rv < 0 ? 0 : (rv > 31 ? 31 : rv);
            const int ic = rc * 32 + j;
            const int ad = dr < 0 ? -dr : dr;
            s7 += ok ? hz7[ic] : 0.f;
            m7 = fmaxf(m7, ok ? hm7[ic] : NEG);
            if (ad <= 2) {
                s5 += ok ? hz5[ic] : 0.f;
                m5 = fmaxf(m5, ok ? hm5[ic] : NEG);
            }
            if (ad <= 1) {
                s3 += ok ? hz3[ic] : 0.f;
                m3 = fmaxf(m3, ok ? hm3[ic] : NEG);
            }
        }
        dst[p] = s3 * (1.f / 9.f) + s5 * (1.f / 25.f) + s7 * (1.f / 49.f) +
                 m3 + m5 + m7;
    }
}

// ---------------------------------------------------------------------------
__device__ __forceinline__ float block_sum256(float v, volatile float* scr) {
    v = dpp_red_add(v);
    const int t = threadIdx.x;
    __syncthreads();
    if ((t & 63) == 0) scr[t >> 6] = v;
    __syncthreads();
    return scr[0] + scr[1] + scr[2] + scr[3];
}

// LayerNorm v4: coalesced tile load, wave-local rows, DPP reductions.
__global__ __launch_bounds__(256) void ln_kernel3(const float* __restrict__ yp,
                                                  const float* __restrict__ g,
                                                  const float* __restrict__ bt,
                                                  unsigned short* __restrict__ ynbf) {
    __shared__ float tile[512][17];
    const int blk = blockIdx.x;           // b*64 + ntile
    const int b = blk >> 6;
    const int n0 = (blk & 63) * 16;
    const int t = threadIdx.x;
#pragma unroll
    for (int r = 0; r < 8; ++r) {
        const int c = r * 64 + (t >> 2);
        const int nn = (t & 3) * 4;
        const float4 v = *reinterpret_cast<const float4*>(
            &yp[((size_t)(b * 512 + c)) * 1024 + n0 + nn]);
        tile[c][nn + 0] = v.x; tile[c][nn + 1] = v.y;
        tile[c][nn + 2] = v.z; tile[c][nn + 3] = v.w;
    }
    const int w = t >> 6, lane = t & 63;
    float gv[8], bv[8];
#pragma unroll
    for (int j = 0; j < 8; j++) {
        gv[j] = g[lane + 64 * j];
        bv[j] = bt[lane + 64 * j];
    }
    __syncthreads();
#pragma unroll
    for (int rr = 0; rr < 4; ++rr) {
        const int n = w * 4 + rr;
        float v[8];
        float ls = 0.f;
#pragma unroll
        for (int j = 0; j < 8; j++) {
            v[j] = tile[lane + 64 * j][n];
            ls += v[j];
        }
        ls = dpp_red_add(ls);
        const float mu = ls * (1.f / 512.f);
        float ls2 = 0.f;
#pragma unroll
        for (int j = 0; j < 8; j++) {
            const float d = v[j] - mu;
            ls2 = fmaf(d, d, ls2);
        }
        ls2 = dpp_red_add(ls2);
        const float rs = rsqrtf(ls2 * (1.f / 512.f) + 1e-5f);
        unsigned short* o = ynbf + ((size_t)(b * 1024 + n0 + n)) * 512;
#pragma unroll
        for (int j = 0; j < 8; j++)
            o[lane + 64 * j] = f2bf((v[j] - mu) * rs * gv[j] + bv[j]);
    }
}

// ---------------------------------------------------------------------------
__global__ __launch_bounds__(256) void pooled_kernel(const float* __restrict__ x,
                                                     float* __restrict__ pooled) {
    __shared__ float scr[4];
    const int bc = blockIdx.x, t = threadIdx.x;
    const float4 v = reinterpret_cast<const float4*>(x + (size_t)bc * 1024)[t];
    const float s = block_sum256(v.x + v.y + v.z + v.w, scr);
    if (t == 0) pooled[bc] = s * (1.f / 1024.f);
}

__global__ __launch_bounds__(128) void mlp_kernel(const float* __restrict__ pooled,
                                                  const float* __restrict__ w1,
                                                  const float* __restrict__ b1,
                                                  const float* __restrict__ w2,
                                                  const float* __restrict__ b2,
                                                  int* __restrict__ kvals) {
    __shared__ float pl[512];
    __shared__ float h1[128];
    __shared__ float lg[8];
    const int b = blockIdx.x, t = threadIdx.x;
#pragma unroll
    for (int i = 0; i < 4; i++) pl[t + i * 128] = pooled[b * 512 + t + i * 128];
    __syncthreads();
    float acc = b1[t];
    for (int i = 0; i < 512; i++) acc = fmaf(pl[i], w1[t * 512 + i], acc);
    h1[t] = fmaxf(acc, 0.f);
    __syncthreads();
    if (t < 8) {
        float a = b2[t];
        for (int i = 0; i < 128; i++) a = fmaf(h1[i], w2[t * 128 + i], a);
        lg[t] = a;
    }
    __syncthreads();
    if (t == 0) {
        float m = lg[0];
#pragma unroll
        for (int h = 1; h < 8; h++) m = fmaxf(m, lg[h]);
        float e[8], s = 0.f;
#pragma unroll
        for (int h = 0; h < 8; h++) { e[h] = expf(lg[h] - m); s += e[h]; }
#pragma unroll
        for (int h = 0; h < 8; h++) {
            const float p = e[h] / s;
            int kv = (int)floorf(p * 1024.f);
            kv = kv < 1 ? 1 : (kv > 1024 ? 1024 : kv);
            kvals[b * 8 + h] = kv;
        }
    }
}

// ---------------------------------------------------------------------------
// All three weight matrices -> bf16 in one launch.
__global__ __launch_bounds__(256) void convw(const float* __restrict__ qw,
                                             const float* __restrict__ kvw,
                                             const float* __restrict__ pw,
                                             unsigned short* __restrict__ dq,
                                             unsigned short* __restrict__ dkv,
                                             unsigned short* __restrict__ dp) {
    const int gid = blockIdx.x * 256 + threadIdx.x;
    const float* s; unsigned short* d; int off;
    if (gid < 65536) { s = qw; d = dq; off = gid * 4; }
    else if (gid < 196608) { s = kvw; d = dkv; off = gid * 4 - 262144; }
    else { s = pw; d = dp; off = gid * 4 - 786432; }
    const float4 v = *reinterpret_cast<const float4*>(&s[off]);
    ushort4 o;
    o.x = f2bf(v.x); o.y = f2bf(v.y); o.z = f2bf(v.z); o.w = f2bf(v.w);
    *reinterpret_cast<ushort4*>(&d[off]) = o;
}

// x (b,c,n) fp32 -> xbf (b,n,c) bf16
__global__ __launch_bounds__(256) void xtrans(const float* __restrict__ x,
                                              unsigned short* __restrict__ xbf) {
    __shared__ float tile[32][36];
    const int blk = blockIdx.x;       // b(3b) | cg(4b) | ng(5b)
    const int ng = blk & 31;
    const int cg = (blk >> 5) & 15;
    const int b = blk >> 9;
    const int c0 = cg * 32, n0 = ng * 32;
    const int t = threadIdx.x;
    {
        const int cc = t >> 3, nn = (t & 7) * 4;
        const float4 v = *reinterpret_cast<const float4*>(
            &x[((size_t)(b * 512 + c0 + cc)) * 1024 + n0 + nn]);
        *reinterpret_cast<float4*>(&tile[cc][nn]) = v;
    }
    __syncthreads();
    {
        const int n = t >> 3, cb = (t & 7) * 4;
        ushort4 o;
        o.x = f2bf(tile[cb + 0][n]); o.y = f2bf(tile[cb + 1][n]);
        o.z = f2bf(tile[cb + 2][n]); o.w = f2bf(tile[cb + 3][n]);
        *reinterpret_cast<ushort4*>(
            &xbf[((size_t)(b * 1024 + n0 + n)) * 512 + c0 + cb]) = o;
    }
}

// ---------------------------------------------------------------------------
// MFMA bf16 GEMM core: C[128x128 tile] = A[M,512] @ W[Nout,512]^T
template <int EPI>
__device__ __forceinline__ void gemm_core(const unsigned short* __restrict__ A,
                                          const unsigned short* __restrict__ W,
                                          const float* __restrict__ bias,
                                          void* __restrict__ out0,
                                          unsigned short* __restrict__ out1,
                                          int Nout, int bx, int by,
                                          unsigned short* As,
                                          unsigned short* Ws) {
    const int t = threadIdx.x;
    const int w = t >> 6, lane = t & 63;
    const int l15 = lane & 15, l4 = lane >> 4;
    const int n0 = bx * 128;
    const int m0 = by * 128;
    const int wm = (w >> 1) * 64, wn = (w & 1) * 64;
    f32x4 acc[4][4];
#pragma unroll
    for (int i = 0; i < 4; i++)
#pragma unroll
        for (int j = 0; j < 4; j++) acc[i][j] = (f32x4){0.f, 0.f, 0.f, 0.f};
    const int lrow = lane >> 3;               // 0..7
    const int lslot = (lane & 7) ^ lrow;      // inverse-swizzled 16B slot
    const unsigned short* aG = A + (size_t)(m0 + lrow) * 512 + lslot * 8;
    const unsigned short* wG = W + (size_t)(n0 + lrow) * 512 + lslot * 8;
#pragma unroll 1
    for (int k0 = 0; k0 < 512; k0 += 64) {
        __syncthreads();
#pragma unroll
        for (int p = 0; p < 4; p++) {
            const int rb = p * 32 + w * 8;
            stage16(aG + (size_t)rb * 512 + k0, &As[rb * 64]);
            stage16(wG + (size_t)rb * 512 + k0, &Ws[rb * 64]);
        }
        __syncthreads();
#pragma unroll
        for (int kk = 0; kk < 2; kk++) {
            bf16x8 af[4], wf[4];
#pragma unroll
            for (int f = 0; f < 4; f++) {
                const int ra = wm + f * 16 + l15;
                af[f] = *reinterpret_cast<const bf16x8*>(
                    &As[ra * 64 + (((kk * 4 + l4) ^ (ra & 7)) << 3)]);
                const int rw = wn + f * 16 + l15;
                wf[f] = *reinterpret_cast<const bf16x8*>(
                    &Ws[rw * 64 + (((kk * 4 + l4) ^ (rw & 7)) << 3)]);
            }
#pragma unroll
            for (int fm = 0; fm < 4; fm++)
#pragma unroll
                for (int fn = 0; fn < 4; fn++)
                    acc[fm][fn] = __builtin_amdgcn_mfma_f32_16x16x32_bf16(
                        af[fm], wf[fn], acc[fm][fn], 0, 0, 0);
        }
    }
    if (EPI == 0) {
        unsigned short* C = (unsigned short*)out0;
#pragma unroll
        for (int fm = 0; fm < 4; fm++) {
            const int row = m0 + wm + fm * 16 + l4 * 4;
#pragma unroll
            for (int fn = 0; fn < 4; fn++) {
                const int col = n0 + wn + fn * 16 + l15;
#pragma unroll
                for (int q = 0; q < 4; q++)
                    C[(size_t)(row + q) * Nout + col] = f2bf(acc[fm][fn][q]);
            }
        }
    } else if (EPI == 1) {
        unsigned short* kb = (unsigned short*)out0;
        const int b = m0 >> 10;
        const int cw = n0 + wn;
        const bool isv = cw >= 512;
        const int hh = (cw & 511) >> 6;
        const size_t bh = (size_t)(b * 8 + hh);
#pragma unroll
        for (int fm = 0; fm < 4; fm++) {
            const int n = (m0 + wm + fm * 16 + l4 * 4) & 1023;
#pragma unroll
            for (int fn = 0; fn < 4; fn++) {
                const int d = fn * 16 + l15;
                if (!isv) {
#pragma unroll
                    for (int q = 0; q < 4; q++)
                        kb[(bh * 1024 + n + q) * 64 + d] = f2bf(acc[fm][fn][q]);
                } else {
                    ushort4 v4;
                    v4.x = f2bf(acc[fm][fn][0]); v4.y = f2bf(acc[fm][fn][1]);
                    v4.z = f2bf(acc[fm][fn][2]); v4.w = f2bf(acc[fm][fn][3]);
                    *reinterpret_cast<ushort4*>(&out1[(bh * 64 + d) * 1024 + n]) = v4;
                }
            }
        }
    } else {
        float* outp = (float*)out0;
        const int b = m0 >> 10;
#pragma unroll
        for (int fm = 0; fm < 4; fm++) {
            const int n = (m0 + wm + fm * 16 + l4 * 4) & 1023;
#pragma unroll
            for (int fn = 0; fn < 4; fn++) {
                const int c = n0 + wn + fn * 16 + l15;
                const float bv = bias[c];
                float4 o;
                o.x = acc[fm][fn][0] + bv; o.y = acc[fm][fn][1] + bv;
                o.z = acc[fm][fn][2] + bv; o.w = acc[fm][fn][3] + bv;
                *reinterpret_cast<float4*>(
                    &outp[((size_t)(b * 512) + c) * 1024 + n]) = o;
            }
        }
    }
}

// Fused kv + q GEMM: blocks 0..511 -> kv (EPI 1), 512..767 -> q (EPI 0).
__global__ __launch_bounds__(256, 4) void gemm_qkv(
    const unsigned short* __restrict__ ynbf,
    const unsigned short* __restrict__ kvwbf,
    const unsigned short* __restrict__ xbf,
    const unsigned short* __restrict__ qwbf,
    unsigned short* __restrict__ kbf,
    unsigned short* __restrict__ vtbf,
    unsigned short* __restrict__ qbf) {
    __shared__ unsigned short As[128 * 64];
    __shared__ unsigned short Ws[128 * 64];
    const int blk = blockIdx.x;
    if (blk < 512) {
        gemm_core<1>(ynbf, kvwbf, nullptr, kbf, vtbf, 1024, blk & 7, blk >> 3,
                     As, Ws);
    } else {
        const int i = blk - 512;
        gemm_core<0>(xbf, qwbf, nullptr, qbf, nullptr, 512, i & 3, i >> 2,
                     As, Ws);
    }
}

// proj GEMM (EPI 2)
__global__ __launch_bounds__(256, 4) void gemm_proj(
    const unsigned short* __restrict__ attbf,
    const unsigned short* __restrict__ pwbf,
    const float* __restrict__ bias,
    float* __restrict__ out) {
    __shared__ unsigned short As[128 * 64];
    __shared__ unsigned short Ws[128 * 64];
    gemm_core<2>(attbf, pwbf, bias, out, nullptr, 512, blockIdx.x, blockIdx.y,
                 As, Ws);
}

// ---------------------------------------------------------------------------
// count of f[i] >= Tf across the wave (wave-uniform result)
__device__ __forceinline__ int cntF(const float* f, float Tf) {
    int c = 0;
#pragma unroll
    for (int i = 0; i < 16; i++)
        c += (int)__popcll(__ballot(f[i] >= Tf));
    return c;
}

// Fused attention v13: attn9 structure with P restrided to 4096B rows so the
// P-overlay touches only the writing wave's own logit row -> the post-phase-2
// barrier is removed (5 barriers instead of 6). Otherwise identical to attn9.
__global__ __launch_bounds__(1024, 8) void attn13(
    const unsigned short* __restrict__ qbf,
    const unsigned short* __restrict__ kbf,
    const unsigned short* __restrict__ vtbf,
    const int* __restrict__ kvals,
    const float* __restrict__ temp,
    unsigned short* __restrict__ attbf) {
    __shared__ float smem[16384];   // 64 KB: logits -> (P bf16 half-rows | partials)
    const int bid = blockIdx.x;
    const int swz = (bid & 7) * 512 + (bid >> 3);   // XCD-contiguous bh groups
    const int bh = swz >> 6;
    const int tile = swz & 63;
    const int b = bh >> 3, h = bh & 7;
    const int n0 = tile * 16;
    const int t = threadIdx.x;
    const int lane = t & 63, w = t >> 6;   // w = 0..15 (also: my query row)
    const int l15 = lane & 15, l4 = lane >> 4;

    const float tempv = temp[h];
    const int kv_s = __builtin_amdgcn_readfirstlane(kvals[b * 8 + h]);

    // ---- Phase 1: QK^T swapped (A=K, B=Q): lane holds 4 consecutive keys ----
    {
        const unsigned short* qp =
            qbf + ((size_t)(b * 1024 + n0 + l15)) * 512 + h * 64 + l4 * 8;
        const bf16x8 qa0 = *reinterpret_cast<const bf16x8*>(qp);
        const bf16x8 qa1 = *reinterpret_cast<const bf16x8*>(qp + 32);
        const unsigned short* kbase = kbf + (size_t)bh * 65536;
#pragma unroll
        for (int f = 0; f < 4; f++) {
            const int key = w * 64 + f * 16 + l15;
            const unsigned short* kp = kbase + (size_t)key * 64 + l4 * 8;
            const bf16x8 kb0 = *reinterpret_cast<const bf16x8*>(kp);
            const bf16x8 kb1 = *reinterpret_cast<const bf16x8*>(kp + 32);
            f32x4 acc = {0.f, 0.f, 0.f, 0.f};
            acc = __builtin_amdgcn_mfma_f32_16x16x32_bf16(kb0, qa0, acc, 0, 0, 0);
            acc = __builtin_amdgcn_mfma_f32_16x16x32_bf16(kb1, qa1, acc, 0, 0, 0);
            const int blkidx = w * 16 + f * 4 + l4;      // 16B block in row
            float4 o;
            o.x = acc[0] * tempv; o.y = acc[1] * tempv;
            o.z = acc[2] * tempv; o.w = acc[3] * tempv;
            *reinterpret_cast<float4*>(
                &smem[l15 * 1024 + ((blkidx ^ (l15 & 7)) << 2)]) = o;
        }
    }
    __syncthreads();

    // ---- Phase 2: my row -> f[16] (unswizzled read); fused stats ----
    float f[16];
    float vmn = 3.402823466e38f, vmx = -3.402823466e38f;
    float fs = 0.f;
#pragma unroll
    for (int i = 0; i < 4; i++) {
        const int gblk = i * 64 + lane;                  // keys gblk*4..+3
        const float4 f0 = *reinterpret_cast<const float4*>(
            &smem[w * 1024 + ((gblk ^ (w & 7)) << 2)]);
        f[4 * i + 0] = f0.x; f[4 * i + 1] = f0.y;
        f[4 * i + 2] = f0.z; f[4 * i + 3] = f0.w;
#pragma unroll
        for (int j = 0; j < 4; j++) {
            const float v = f[4 * i + j];
            vmn = fminf(vmn, v);
            vmx = fmaxf(vmx, v);
            fs += v;
        }
    }
    // NO barrier here: P row w (bytes w*4096 .. +2047) overlays only the
    // first half of logit row w, which only THIS wave reads (done above).

    vmn = dpp_red_min(vmn);
    vmx = dpp_red_max(vmx);
    fs = dpp_red_add(fs);

    // ---- Phase 3: exact threshold (scalar control flow) ----
    float thrF;
    {
        const int cmx = __builtin_amdgcn_readfirstlane(cntF(f, vmx));
        if (cmx >= kv_s) {
            thrF = vmx;
        } else if (kv_s >= 1024) {
            thrF = vmn;
        } else {
            const float mu = fs * (1.f / 1024.f);
            const float sg = fmaxf((vmx - mu) * 0.3125f, 1e-12f);
            const float pq = (float)kv_s * (1.f / 1024.f);
            const float pc = pq < 0.5f ? pq : 1.f - pq;
            const float tt = sqrtf(-2.f * __logf(fmaxf(pc, 1e-20f)));
            float zq = tt - (2.30753f + 0.27061f * tt) /
                            (1.f + tt * (0.99229f + 0.04481f * tt));
            zq = pq < 0.5f ? zq : -zq;
            unsigned lo = xform_u(__float_as_uint(vmn));
            unsigned hi = xform_u(__float_as_uint(vmx));
            float glo = (float)(1024 - kv_s), ghi = (float)(cmx - kv_s);
            int side = 0;
            unsigned T = xform_u(__float_as_uint(fmaf(zq, sg, mu)));
            if (T <= lo) T = lo + 1;
            if (T >= hi) T = hi - 1;
            thrF = vmn;
#pragma unroll 1
            for (int it = 0; it < 48; ++it) {
                const float Tf = unxform_f(T);
                const int ct = __builtin_amdgcn_readfirstlane(cntF(f, Tf));
                if (ct == kv_s) { thrF = Tf; break; }
                if (ct > kv_s) {
                    lo = T; glo = (float)(ct - kv_s);
                    if (side == 1) ghi *= 0.5f;
                    side = 1;
                } else {
                    hi = T; ghi = (float)(ct - kv_s);
                    if (side == -1) glo *= 0.5f;
                    side = -1;
                }
                if (hi - lo <= 1u) { thrF = unxform_f(lo); break; }
                if ((it & 3) == 3) {
                    T = lo + ((hi - lo) >> 1);
                } else {
                    const float flo = unxform_f(lo), fhi = unxform_f(hi);
                    const float fr = glo / (glo - ghi);
                    T = xform_u(__float_as_uint(fmaf(fr, fhi - flo, flo)));
                    if (T <= lo) T = lo + 1;
                    if (T >= hi) T = hi - 1;
                }
            }
        }
    }

    // ---- Phase 3b: softmax(attn*mask) in place -> bf16 P (cvt_pk, swizzled)
    //      P row w lives at ushort offset w*2048 (byte w*4096) = first half of
    //      this wave's own logit row.
    unsigned short* P = (unsigned short*)smem;
    {
        const float mx = (thrF > vmn) ? fmaxf(vmx, 0.f) : vmx;
        float s = 0.f;
#pragma unroll
        for (int i = 0; i < 16; i++) {
            const float g = (f[i] >= thrF) ? f[i] : 0.f;
            const float e = __expf(g - mx);
            f[i] = e;
            s += e;
        }
        s = dpp_red_add(s);
        const float inv = 1.f / s;
#pragma unroll
        for (int g4 = 0; g4 < 4; g4++) {
            unsigned lo32, hi32;
            const float a0 = f[g4 * 4 + 0] * inv, a1 = f[g4 * 4 + 1] * inv;
            const float a2 = f[g4 * 4 + 2] * inv, a3 = f[g4 * 4 + 3] * inv;
            asm("v_cvt_pk_bf16_f32 %0, %1, %2" : "=v"(lo32) : "v"(a0), "v"(a1));
            asm("v_cvt_pk_bf16_f32 %0, %1, %2" : "=v"(hi32) : "v"(a2), "v"(a3));
            uint2 pk; pk.x = lo32; pk.y = hi32;
            *reinterpret_cast<uint2*>(
                &P[w * 2048 + ((((lane >> 1) + 32 * g4) ^ (w & 7)) << 3) +
                   (lane & 1) * 4]) = pk;
        }
    }
    __syncthreads();

    // ---- Phase 4: PV; wave w -> (kseg = w>>2 of 256 keys, cf = w&3 of 16 d) ----
    const int kseg = w >> 2, cf = w & 3;
    f32x4 pacc = {0.f, 0.f, 0.f, 0.f};
    const unsigned short* vtb =
        vtbf + (size_t)bh * 65536 + (size_t)(cf * 16 + l15) * 1024;
#pragma unroll
    for (int s8 = 0; s8 < 8; s8++) {
        const int kb0 = kseg * 256 + s8 * 32;
        const int g = (kb0 >> 3) + l4;
        const bf16x8 pa = *reinterpret_cast<const bf16x8*>(
            &P[l15 * 2048 + ((g ^ (l15 & 7)) << 3)]);
        const bf16x8 vb = *reinterpret_cast<const bf16x8*>(vtb + kb0 + l4 * 8);
        pacc = __builtin_amdgcn_mfma_f32_16x16x32_bf16(pa, vb, pacc, 0, 0, 0);
    }
    __syncthreads();     // P reads done -> reuse smem for partials
    float* part = smem;  // [4 kseg][16 row][66]
#pragma unroll
    for (int q = 0; q < 4; q++)
        part[kseg * 1056 + (l4 * 4 + q) * 66 + cf * 16 + l15] = pacc[q];
    __syncthreads();
    {
        const float s = part[w * 66 + lane] + part[1056 + w * 66 + lane] +
                        part[2112 + w * 66 + lane] + part[3168 + w * 66 + lane];
        attbf[((size_t)(b * 1024 + n0 + w)) * 512 + h * 64 + lane] = f2bf(s);
    }
}

// ---------------------------------------------------------------------------
extern "C" void kernel_launch(void* const* d_in, const int* in_sizes, int n_in,
                              void* d_out, int out_size, void* d_ws, size_t ws_size,
                              hipStream_t stream) {
    const float* x = (const float*)d_in[0];
    const float* y = (const float*)d_in[1];
    const float* temp = (const float*)d_in[2];
    const float* q_w = (const float*)d_in[3];
    const float* kv_w = (const float*)d_in[4];
    const float* proj_w = (const float*)d_in[5];
    const float* proj_b = (const float*)d_in[6];
    const float* dk_w1 = (const float*)d_in[7];
    const float* dk_b1 = (const float*)d_in[8];
    const float* dk_w2 = (const float*)d_in[9];
    const float* dk_b2 = (const float*)d_in[10];
    const float* ln_g = (const float*)d_in[11];
    const float* ln_b = (const float*)d_in[12];
    float* out = (float*)d_out;
    float* ws = (float*)d_ws;

    float* yp = ws;
    unsigned short* ynbf = (unsigned short*)(ws + 4194304);
    unsigned short* xbf = (unsigned short*)(ws + 6291456);
    unsigned short* qbf = (unsigned short*)(ws + 8388608);
    unsigned short* attbf = (unsigned short*)(ws + 10485760);
    unsigned short* qwbf = (unsigned short*)(ws + 12582912);
    unsigned short* kvwbf = (unsigned short*)(ws + 12713984);
    unsigned short* pwbf = (unsigned short*)(ws + 12976128);
    float* pooled = ws + 13107200;
    int* kvals = (int*)(ws + 13111296);
    unsigned short* kbf = (unsigned short*)ws;               // reuse yp after ln
    unsigned short* vtbf = (unsigned short*)(ws + 2097152);  // reuse yp after ln

    pool_kernel<<<4096, 256, 0, stream>>>(y, yp);
    xtrans<<<4096, 256, 0, stream>>>(x, xbf);
    pooled_kernel<<<4096, 256, 0, stream>>>(x, pooled);
    mlp_kernel<<<8, 128, 0, stream>>>(pooled, dk_w1, dk_b1, dk_w2, dk_b2, kvals);
    convw<<<1024, 256, 0, stream>>>(q_w, kv_w, proj_w, qwbf, kvwbf, pwbf);
    ln_kernel3<<<512, 256, 0, stream>>>(yp, ln_g, ln_b, ynbf);
    gemm_qkv<<<768, 256, 0, stream>>>(ynbf, kvwbf, xbf, qwbf, kbf, vtbf, qbf);
    attn13<<<4096, 1024, 0, stream>>>(qbf, kbf, vtbf, kvals, temp, attbf);
    gemm_proj<<<dim3(4, 64), 256, 0, stream>>>(attbf, pwbf, proj_b, out);
}